// Round 3
// baseline (743.710 us; speedup 1.0000x reference)
//
#include <hip/hip_runtime.h>

#define NPTS 16384
#define TH 33.33f

typedef __attribute__((ext_vector_type(8)))  __bf16 bf16x8;
typedef __attribute__((ext_vector_type(16))) float  f32x16;

__device__ __forceinline__ unsigned short f2bf(float x) {
    unsigned u = __float_as_uint(x);
    u += 0x7FFFu + ((u >> 16) & 1u);
    return (unsigned short)(u >> 16);
}
__device__ __forceinline__ float bf2f(unsigned short h) {
    return __uint_as_float(((unsigned)h) << 16);
}

union U8 { unsigned short s[8]; uint4 v; };

// ws layout: mats ushort[2b][4roles][512 tiles][512]  (4 MB)  roles: 0=Asrc 1=Atgt 2=Bsrc 3=Btgt
//            harr float[2b][2set][NPTS]                (256 KB)
//            rows float[4db][2half][NPTS]              (512 KB)
// fragment order: elem = tile*512 + (g*32 + (p&31))*8 + j, with k = g*8 + j
// A-role k: [qh(3), ql(3), qh(3), 1,1,1, 0..0]   B-role k: [ph(3), ph(3), pl(3), -hp0,-hp1,-hp2, 0..0]
// => MFMA score s = qh.ph + ql.ph + qh.pl - hp ~= q.p - hp ;  d^2 = 2*(hq - s)

__global__ __launch_bounds__(256) void prep_kernel(const float* __restrict__ src,
        const float* __restrict__ tgt, unsigned short* __restrict__ mats,
        float* __restrict__ harr, float* __restrict__ out) {
    int t = blockIdx.x * 256 + threadIdx.x;       // 65536 threads
    if (t < 2) out[t] = 0.0f;
    int b = t >> 15, set = (t >> 14) & 1, p = t & (NPTS - 1);
    const float* pc = (set ? tgt : src) + ((size_t)b * NPTS + p) * 3;
    float x = pc[0], y = pc[1], z = pc[2];
    float hp = 0.5f * fmaf(z, z, fmaf(y, y, x * x));
    harr[(b * 2 + set) * NPTS + p] = hp;
    unsigned short xh = f2bf(x), yh = f2bf(y), zh = f2bf(z);
    unsigned short xl = f2bf(x - bf2f(xh)), yl = f2bf(y - bf2f(yh)), zl = f2bf(z - bf2f(zh));
    float r = hp;
    unsigned short h0 = f2bf(r); r -= bf2f(h0);
    unsigned short h1 = f2bf(r); r -= bf2f(h1);
    unsigned short h2 = f2bf(r);
    unsigned short n0 = h0 ^ 0x8000, n1 = h1 ^ 0x8000, n2 = h2 ^ 0x8000;
    const unsigned short one = 0x3F80;
    U8 a0, a1, c0, c1;
    a0.s[0]=xh; a0.s[1]=yh; a0.s[2]=zh; a0.s[3]=xl; a0.s[4]=yl; a0.s[5]=zl; a0.s[6]=xh; a0.s[7]=yh;
    a1.s[0]=zh; a1.s[1]=one; a1.s[2]=one; a1.s[3]=one; a1.s[4]=0; a1.s[5]=0; a1.s[6]=0; a1.s[7]=0;
    c0.s[0]=xh; c0.s[1]=yh; c0.s[2]=zh; c0.s[3]=xh; c0.s[4]=yh; c0.s[5]=zh; c0.s[6]=xl; c0.s[7]=yl;
    c1.s[0]=zl; c1.s[1]=n0; c1.s[2]=n1; c1.s[3]=n2; c1.s[4]=0; c1.s[5]=0; c1.s[6]=0; c1.s[7]=0;
    size_t tile = p >> 5; int ll = p & 31;
    size_t iA = ((size_t)(b * 4 + set))     * NPTS * 16 + tile * 512 + ll * 8;
    size_t iB = ((size_t)(b * 4 + 2 + set)) * NPTS * 16 + tile * 512 + ll * 8;
    *(uint4*)(mats + iA)       = a0.v;
    *(uint4*)(mats + iA + 256) = a1.v;
    *(uint4*)(mats + iB)       = c0.v;
    *(uint4*)(mats + iB + 256) = c1.v;
}

__global__ __launch_bounds__(256) void gemm_kernel(const unsigned short* __restrict__ mats,
        const float* __restrict__ harr, float* __restrict__ rows) {
    const int db = blockIdx.y, dir = db >> 1, b = db & 1;
    const int rowblock = blockIdx.x >> 1, hf = blockIdx.x & 1;
    const int tid = threadIdx.x, wave = tid >> 6, lane = tid & 63;
    const unsigned short* Am = mats + ((size_t)(b * 4 + dir))     * NPTS * 16;
    const unsigned short* Bm = mats + ((size_t)(b * 4 + 3 - dir)) * NPTS * 16;

    const int rt0 = rowblock * 8 + wave * 2;      // 2 row-tiles (64 rows) per wave
    bf16x8 a0 = *(const bf16x8*)(Am + (size_t)rt0 * 512 + lane * 8);
    bf16x8 a1 = *(const bf16x8*)(Am + (size_t)(rt0 + 1) * 512 + lane * 8);

    __shared__ alignas(16) unsigned short sbuf[2][16384];   // 2 x 32 KB chunks

    const uint4* gB = (const uint4*)(Bm + (size_t)hf * 256 * 512);  // this half: 256 tiles
    uint4 pre[8];
#pragma unroll
    for (int i = 0; i < 8; i++) pre[i] = gB[i * 256 + tid];
#pragma unroll
    for (int i = 0; i < 8; i++) ((uint4*)sbuf[0])[i * 256 + tid] = pre[i];
    __syncthreads();

    f32x16 m0 = -3.0e38f, m1 = -3.0e38f;
    const f32x16 zc = 0.0f;

    for (int c = 0; c < 8; c++) {                 // 8 chunks x 32 tiles
        if (c < 7) {
            const uint4* gc = gB + (size_t)(c + 1) * 2048;
#pragma unroll
            for (int i = 0; i < 8; i++) pre[i] = gc[i * 256 + tid];
        }
        const unsigned short* bb = sbuf[c & 1];
#pragma unroll
        for (int pt = 0; pt < 16; pt++) {         // 2 col-tiles per iter
            bf16x8 q0 = *(const bf16x8*)(bb + pt * 1024 + lane * 8);
            bf16x8 q1 = *(const bf16x8*)(bb + pt * 1024 + 512 + lane * 8);
            f32x16 d0 = __builtin_amdgcn_mfma_f32_32x32x16_bf16(a0, q0, zc, 0, 0, 0);
            f32x16 d1 = __builtin_amdgcn_mfma_f32_32x32x16_bf16(a0, q1, zc, 0, 0, 0);
#pragma unroll
            for (int j = 0; j < 16; j++) m0[j] = fmaxf(fmaxf(d0[j], d1[j]), m0[j]);  // v_max3
            d0 = __builtin_amdgcn_mfma_f32_32x32x16_bf16(a1, q0, zc, 0, 0, 0);
            d1 = __builtin_amdgcn_mfma_f32_32x32x16_bf16(a1, q1, zc, 0, 0, 0);
#pragma unroll
            for (int j = 0; j < 16; j++) m1[j] = fmaxf(fmaxf(d0[j], d1[j]), m1[j]);
        }
        __syncthreads();
        if (c < 7) {
#pragma unroll
            for (int i = 0; i < 8; i++) ((uint4*)sbuf[(c + 1) & 1])[i * 256 + tid] = pre[i];
            __syncthreads();
        }
    }

    // epilogue: cross-lane row-max via per-wave LDS scratch (pad 33 -> conflict-free)
    float* scratch = ((float*)sbuf) + wave * 2112;   // 64 rows * 33 floats
    const int g = lane >> 5, cc = lane & 31;
#pragma unroll
    for (int j = 0; j < 16; j++) {
        int r0 = (j & 3) + 8 * (j >> 2) + 4 * g;     // C/D row map (m74/m101)
        scratch[r0 * 33 + cc]        = m0[j];
        scratch[(r0 + 32) * 33 + cc] = m1[j];
    }
    int rr = g * 32 + cc;                            // this lane reduces row rr
    float mx = -3.0e38f;
#pragma unroll
    for (int k = 0; k < 32; k++) mx = fmaxf(mx, scratch[rr * 33 + k]);
    int grow = rowblock * 256 + wave * 64 + rr;
    float hq = harr[(b * 2 + dir) * NPTS + grow];
    float d2 = 2.0f * (hq - mx);
    float d = fminf(sqrtf(fmaxf(d2, 0.0f)), TH);
    rows[((size_t)(db * 2 + hf)) * NPTS + grow] = d;
}

__global__ __launch_bounds__(256) void merge_kernel(const float* __restrict__ rows,
                                                    float* __restrict__ out) {
    int i = blockIdx.x * 256 + threadIdx.x;  // 16384 threads, one src/tgt row each per db
    float acc0 = 0.0f, acc1 = 0.0f;
#pragma unroll
    for (int db = 0; db < 4; db++) {
        const float* r0 = rows + (size_t)(db * 2 + 0) * NPTS;
        const float* r1 = rows + (size_t)(db * 2 + 1) * NPTS;
        float d = fminf(r0[i], r1[i]);           // min over col-halves
        if (db & 1) acc1 += d; else acc0 += d;
    }
#pragma unroll
    for (int off = 32; off > 0; off >>= 1) {
        acc0 += __shfl_down(acc0, off, 64);
        acc1 += __shfl_down(acc1, off, 64);
    }
    __shared__ float w0[4], w1[4];
    int wv = threadIdx.x >> 6;
    if ((threadIdx.x & 63) == 0) { w0[wv] = acc0; w1[wv] = acc1; }
    __syncthreads();
    if (threadIdx.x == 0) {
        float s0 = w0[0] + w0[1] + w0[2] + w0[3];
        float s1 = w1[0] + w1[1] + w1[2] + w1[3];
        const float inv = 1.0f / (2.0f * NPTS);
        atomicAdd(&out[0], s0 * inv);
        atomicAdd(&out[1], s1 * inv);
    }
}

extern "C" void kernel_launch(void* const* d_in, const int* in_sizes, int n_in,
                              void* d_out, int out_size, void* d_ws, size_t ws_size,
                              hipStream_t stream) {
    const float* src = (const float*)d_in[0];
    const float* tgt = (const float*)d_in[1];
    float* out = (float*)d_out;
    unsigned short* mats = (unsigned short*)d_ws;                       // 4 MB
    float* harr = (float*)((char*)d_ws + 4194304);                      // 256 KB
    float* rows = (float*)((char*)d_ws + 4194304 + 262144);             // 512 KB

    prep_kernel<<<256, 256, 0, stream>>>(src, tgt, mats, harr, out);
    gemm_kernel<<<dim3(128, 4), 256, 0, stream>>>(mats, harr, rows);
    merge_kernel<<<64, 256, 0, stream>>>(rows, out);
}

// Round 4
// 102.855 us; speedup vs baseline: 7.2307x; 7.2307x over previous
//
#include <hip/hip_runtime.h>

#define NPTS 16384
#define TH 33.33f

typedef __attribute__((ext_vector_type(8)))  __bf16 bf16x8;
typedef __attribute__((ext_vector_type(16))) float  f32x16;

__device__ __forceinline__ unsigned short f2bf(float x) {
    unsigned u = __float_as_uint(x);
    u += 0x7FFFu + ((u >> 16) & 1u);
    return (unsigned short)(u >> 16);
}
__device__ __forceinline__ float bf2f(unsigned short h) {
    return __uint_as_float(((unsigned)h) << 16);
}

union U8 { unsigned short s[8]; uint4 v; };

// ws: mats ushort[2b][4roles][512 tiles][512] (4 MB), harr float[2b][2set][NPTS] (256 KB),
//     d2min uint[4db][NPTS] (256 KB; clamped-distance float bits, nonneg -> uint-ordered)
// fragment: elem = tile*512 + (g*32 + (p&31))*8 + j, k = g*8+j
// A k: [qh(3), ql(3), qh(2) | zh, 1,1,1, 0,0,0,0]   B k: [ph(3), ph(3), pl(2) | zl, -hp0,-hp1,-hp2, 0..0]
// MFMA score s = qh.ph + ql.ph + qh.pl - hp ~= q.p - hp ;  d^2 = 2*(hq - s)

__global__ __launch_bounds__(256) void prep_kernel(const float* __restrict__ src,
        const float* __restrict__ tgt, unsigned short* __restrict__ mats,
        float* __restrict__ harr, unsigned int* __restrict__ d2min,
        float* __restrict__ out) {
    int t = blockIdx.x * 256 + threadIdx.x;       // 65536 threads
    if (t < 2) out[t] = 0.0f;
    d2min[t] = 0x7F800000u;                       // +inf init (4*NPTS entries)
    int b = t >> 15, set = (t >> 14) & 1, p = t & (NPTS - 1);
    const float* pc = (set ? tgt : src) + ((size_t)b * NPTS + p) * 3;
    float x = pc[0], y = pc[1], z = pc[2];
    float hp = 0.5f * fmaf(z, z, fmaf(y, y, x * x));
    harr[(b * 2 + set) * NPTS + p] = hp;
    unsigned short xh = f2bf(x), yh = f2bf(y), zh = f2bf(z);
    unsigned short xl = f2bf(x - bf2f(xh)), yl = f2bf(y - bf2f(yh)), zl = f2bf(z - bf2f(zh));
    float r = hp;
    unsigned short h0 = f2bf(r); r -= bf2f(h0);
    unsigned short h1 = f2bf(r); r -= bf2f(h1);
    unsigned short h2 = f2bf(r);
    unsigned short n0 = h0 ^ 0x8000, n1 = h1 ^ 0x8000, n2 = h2 ^ 0x8000;
    const unsigned short one = 0x3F80;
    U8 a0, a1, c0, c1;
    a0.s[0]=xh; a0.s[1]=yh; a0.s[2]=zh; a0.s[3]=xl; a0.s[4]=yl; a0.s[5]=zl; a0.s[6]=xh; a0.s[7]=yh;
    a1.s[0]=zh; a1.s[1]=one; a1.s[2]=one; a1.s[3]=one; a1.s[4]=0; a1.s[5]=0; a1.s[6]=0; a1.s[7]=0;
    c0.s[0]=xh; c0.s[1]=yh; c0.s[2]=zh; c0.s[3]=xh; c0.s[4]=yh; c0.s[5]=zh; c0.s[6]=xl; c0.s[7]=yl;
    c1.s[0]=zl; c1.s[1]=n0; c1.s[2]=n1; c1.s[3]=n2; c1.s[4]=0; c1.s[5]=0; c1.s[6]=0; c1.s[7]=0;
    size_t tile = p >> 5; int ll = p & 31;
    size_t iA = ((size_t)(b * 4 + set))     * NPTS * 16 + tile * 512 + ll * 8;
    size_t iB = ((size_t)(b * 4 + 2 + set)) * NPTS * 16 + tile * 512 + ll * 8;
    *(uint4*)(mats + iA)       = a0.v;
    *(uint4*)(mats + iA + 256) = a1.v;
    *(uint4*)(mats + iB)       = c0.v;
    *(uint4*)(mats + iB + 256) = c1.v;
}

#define FOLD(MM, AA) { \
    f32x16 t0 = __builtin_amdgcn_mfma_f32_32x32x16_bf16(AA, q0, zc, 0, 0, 0); \
    f32x16 t1 = __builtin_amdgcn_mfma_f32_32x32x16_bf16(AA, q1, zc, 0, 0, 0); \
    _Pragma("unroll") for (int j = 0; j < 16; j++) MM[j] = fmaxf(fmaxf(t0[j], t1[j]), MM[j]); }

#define EPILOG(MM, P) { \
    float* sc = &scratch[wave][0][0]; \
    _Pragma("unroll") for (int j = 0; j < 16; j++) { \
        int r0 = (j & 3) + 8 * (j >> 2) + 4 * g; sc[r0 * 33 + cc] = MM[j]; } \
    __syncthreads(); \
    const float* sr = &scratch[wave][0][0] + cc * 33 + g * 16; \
    float mx = -3.0e38f; \
    _Pragma("unroll") for (int k = 0; k < 16; k++) mx = fmaxf(mx, sr[k]); \
    mx = fmaxf(mx, __shfl_xor(mx, 32, 64)); \
    if (lane < 32) { \
        int grow = (rt0 + P) * 32 + lane; \
        float hq = hqbase[grow]; \
        float d2 = 2.0f * (hq - mx); \
        float d = fminf(sqrtf(fmaxf(d2, 0.0f)), TH); \
        atomicMin(&dmin[grow], __float_as_uint(d)); } \
    __syncthreads(); }

__global__ __launch_bounds__(256, 3) void gemm_kernel(const unsigned short* __restrict__ mats,
        const float* __restrict__ harr, unsigned int* __restrict__ d2min) {
    const int db = blockIdx.y, dir = db >> 1, b = db & 1;
    const int rowblock = blockIdx.x >> 3, seg = blockIdx.x & 7;
    const int tid = threadIdx.x, wave = tid >> 6, lane = tid & 63;
    const int g = lane >> 5, cc = lane & 31;
    const unsigned short* Am = mats + ((size_t)(b * 4 + dir))     * NPTS * 16;
    const unsigned short* Bm = mats + ((size_t)(b * 4 + 3 - dir)) * NPTS * 16;

    const int rt0 = rowblock * 16 + wave * 4;     // 4 row-tiles = 128 rows per wave
    bf16x8 a0 = *(const bf16x8*)(Am + (size_t)(rt0 + 0) * 512 + lane * 8);
    bf16x8 a1 = *(const bf16x8*)(Am + (size_t)(rt0 + 1) * 512 + lane * 8);
    bf16x8 a2 = *(const bf16x8*)(Am + (size_t)(rt0 + 2) * 512 + lane * 8);
    bf16x8 a3 = *(const bf16x8*)(Am + (size_t)(rt0 + 3) * 512 + lane * 8);

    __shared__ alignas(16) unsigned short sbuf[8192];      // 16 KB stage (16 col-tiles)
    __shared__ float scratch[4][32][33];                   // 16.9 KB epilogue

    f32x16 m0 = -3.0e38f, m1 = -3.0e38f, m2 = -3.0e38f, m3 = -3.0e38f;
    const f32x16 zc = 0.0f;

    const unsigned short* Bseg = Bm + (size_t)seg * 64 * 512;   // 64 col-tiles per segment

    for (int c = 0; c < 4; ++c) {                 // 4 chunks x 16 col-tiles
        const char* gbase = (const char*)(Bseg + (size_t)c * 16 * 512);
#pragma unroll
        for (int i = 0; i < 4; i++) {             // 256 thr x 16B x 4 = 16 KB, zero VGPR cost
            __builtin_amdgcn_global_load_lds(
                (const __attribute__((address_space(1))) unsigned int*)(gbase + i * 4096 + tid * 16),
                (__attribute__((address_space(3))) unsigned int*)((char*)sbuf + i * 4096 + tid * 16),
                16, 0, 0);
        }
        __syncthreads();
#pragma unroll 1
        for (int pt = 0; pt < 8; ++pt) {          // 2 col-tiles per iter
            bf16x8 q0 = *(const bf16x8*)(sbuf + pt * 1024 + lane * 8);
            bf16x8 q1 = *(const bf16x8*)(sbuf + pt * 1024 + 512 + lane * 8);
            FOLD(m0, a0)
            FOLD(m1, a1)
            FOLD(m2, a2)
            FOLD(m3, a3)
        }
        __syncthreads();
    }

    const float* hqbase = harr + (size_t)(b * 2 + dir) * NPTS;
    unsigned int* dmin = d2min + (size_t)db * NPTS;
    EPILOG(m0, 0)
    EPILOG(m1, 1)
    EPILOG(m2, 2)
    EPILOG(m3, 3)
}

__global__ __launch_bounds__(256) void merge_kernel(const unsigned int* __restrict__ d2min,
                                                    float* __restrict__ out) {
    int i = blockIdx.x * 256 + threadIdx.x;       // 16384 threads
    float a0 = __uint_as_float(d2min[0 * NPTS + i]) + __uint_as_float(d2min[2 * NPTS + i]);
    float a1 = __uint_as_float(d2min[1 * NPTS + i]) + __uint_as_float(d2min[3 * NPTS + i]);
#pragma unroll
    for (int off = 32; off > 0; off >>= 1) {
        a0 += __shfl_down(a0, off, 64);
        a1 += __shfl_down(a1, off, 64);
    }
    __shared__ float w0[4], w1[4];
    int wv = threadIdx.x >> 6;
    if ((threadIdx.x & 63) == 0) { w0[wv] = a0; w1[wv] = a1; }
    __syncthreads();
    if (threadIdx.x == 0) {
        const float inv = 1.0f / (2.0f * NPTS);
        atomicAdd(&out[0], (w0[0] + w0[1] + w0[2] + w0[3]) * inv);
        atomicAdd(&out[1], (w1[0] + w1[1] + w1[2] + w1[3]) * inv);
    }
}

extern "C" void kernel_launch(void* const* d_in, const int* in_sizes, int n_in,
                              void* d_out, int out_size, void* d_ws, size_t ws_size,
                              hipStream_t stream) {
    const float* src = (const float*)d_in[0];
    const float* tgt = (const float*)d_in[1];
    float* out = (float*)d_out;
    unsigned short* mats = (unsigned short*)d_ws;                        // 4 MB
    float* harr = (float*)((char*)d_ws + 4194304);                       // 256 KB
    unsigned int* d2min = (unsigned int*)((char*)d_ws + 4194304 + 262144); // 256 KB

    prep_kernel<<<256, 256, 0, stream>>>(src, tgt, mats, harr, d2min, out);
    gemm_kernel<<<dim3(256, 4), 256, 0, stream>>>(mats, harr, d2min);
    merge_kernel<<<64, 256, 0, stream>>>(d2min, out);
}